// Round 1
// 619.754 us; speedup vs baseline: 1.0655x; 1.0655x over previous
//
#include <hip/hip_runtime.h>

// Point2DirSum: directional (hor/ver/diag/adiag) length-5 box sums with zero
// padding. in: (N,C,H,W) fp32, out: (N,4C,H,W) fp32, channel-concat order
// [hor, ver, diag, adiag].
//
// Memory-bound: 134 MB read + 537 MB write (~108 us floor @ 6.3 TB/s).
// This revision targets occupancy: TH 64->32 cuts LDS 35.9->19.0 KB
// (4 -> 8 blocks/CU) and the compute is restructured as streaming
// accumulation (no 5x8 register patch) + __launch_bounds__(256,8) to hold
// VGPRs <= 64 so 8 waves/SIMD are actually resident.

constexpr int N = 128, C = 16, H = 128, W = 128;
constexpr int TH = 32, TW = 128;
constexpr int HALO = 2;
constexpr int LH = TH + 2 * HALO;   // 36
constexpr int LW = TW + 2 * HALO;   // 132 (row stride 528 B, 16B-aligned)

__global__ __launch_bounds__(256, 8)
void Point2DirSum_kernel(const float* __restrict__ in, float* __restrict__ out) {
    __shared__ __align__(16) float tile[LH * LW];   // 19,008 B -> 8 blocks/CU
    const int tid = threadIdx.x;
    constexpr int TILES_PER_IMG = H / TH;            // 4
    const int img = blockIdx.x / TILES_PER_IMG;      // n*C + c
    const int t   = blockIdx.x % TILES_PER_IMG;
    const int h0  = t * TH;
    const float* __restrict__ inp = in + (size_t)img * H * W;

    // Cooperative load, zero-filled halo (zero padding semantics).
    for (int idx = tid; idx < LH * LW; idx += 256) {
        const int r  = idx / LW;                     // const divide -> magic mul
        const int cc = idx - r * LW;
        const int h  = h0 + r - HALO;
        const int w  = cc - HALO;
        float v = 0.0f;
        if ((unsigned)h < (unsigned)H && (unsigned)w < (unsigned)W)
            v = inp[h * W + w];
        tile[idx] = v;
    }
    __syncthreads();

    const int n = img / C;
    const int c = img - n * C;
    float* __restrict__ outp = out + (((size_t)n * 4 * C + c) * (size_t)H) * W;
    const size_t plane = (size_t)C * H * W;          // stride between dir blocks

    // tile[r][cc] == xp_padded[h0 + r][cc]  (xp = zero-padded input, pad=2)
    // output (h = h0+rl, w = w4+j):
    //   hor  = sum_d tile[rl+2][w4+j+d]
    //   ver  = sum_d tile[rl+d][w4+j+2]
    //   diag = sum_d tile[rl+d][w4+j+d]
    //   adiag= sum_d tile[rl+d][w4+j+4-d]
    // Streaming accumulation: consume each row's 8 floats immediately; only
    // the 16 accumulators stay live across d  -> VGPR-lean (target <= 64).
    constexpr int GROUPS = TH * TW / 4;              // 1024 float4-groups
    for (int g = tid; g < GROUPS; g += 256) {
        const int rl = g >> 5;                       // 32 groups per row
        const int w4 = (g & 31) * 4;

        float ho[4], ve[4], di[4], ad[4];
        #pragma unroll
        for (int j = 0; j < 4; ++j) { ve[j] = 0.f; di[j] = 0.f; ad[j] = 0.f; }

        #pragma unroll
        for (int d = 0; d < 5; ++d) {
            const float4 a = *(const float4*)&tile[(rl + d) * LW + w4];
            const float4 b = *(const float4*)&tile[(rl + d) * LW + w4 + 4];
            float e[8];
            e[0] = a.x; e[1] = a.y; e[2] = a.z; e[3] = a.w;
            e[4] = b.x; e[5] = b.y; e[6] = b.z; e[7] = b.w;
            #pragma unroll
            for (int j = 0; j < 4; ++j) {
                ve[j] += e[j + 2];                   // vertical
                di[j] += e[j + d];                   // main diagonal
                ad[j] += e[j + 4 - d];               // anti-diagonal
            }
            if (d == 2) {                            // horizontal, same add order
                #pragma unroll
                for (int j = 0; j < 4; ++j)
                    ho[j] = e[j] + e[j + 1] + e[j + 2] + e[j + 3] + e[j + 4];
            }
        }

        const int h = h0 + rl;
        const size_t o = (size_t)h * W + w4;
        *(float4*)&outp[o]             = make_float4(ho[0], ho[1], ho[2], ho[3]);
        *(float4*)&outp[o + plane]     = make_float4(ve[0], ve[1], ve[2], ve[3]);
        *(float4*)&outp[o + 2 * plane] = make_float4(di[0], di[1], di[2], di[3]);
        *(float4*)&outp[o + 3 * plane] = make_float4(ad[0], ad[1], ad[2], ad[3]);
    }
}

extern "C" void kernel_launch(void* const* d_in, const int* in_sizes, int n_in,
                              void* d_out, int out_size, void* d_ws, size_t ws_size,
                              hipStream_t stream) {
    const float* in = (const float*)d_in[0];
    float* out = (float*)d_out;
    const int grid = N * C * (H / TH);               // 8192 blocks
    Point2DirSum_kernel<<<grid, 256, 0, stream>>>(in, out);
}

// Round 3
// 607.984 us; speedup vs baseline: 1.0861x; 1.0194x over previous
//
#include <hip/hip_runtime.h>

// Point2DirSum: directional (hor/ver/diag/adiag) length-5 box sums with zero
// padding. in: (N,C,H,W) fp32, out: (N,4C,H,W) fp32, channel-concat order
// [hor, ver, diag, adiag].
//
// R3 = R2 with the compile fix: __builtin_nontemporal_store requires a
// native vector type, not HIP_vector_type<float,4>. Use ext_vector_type.
//
// Theory (unchanged): the LDS-tiled kernel was structure-bound (load phase
// -> barrier -> compute phase serializes HBM latency), not pipe-bound.
// This version is shaped like the fill kernel that hits 78% of HBM peak:
// no LDS, no barrier, each thread computes a 4-row x 4-col output patch
// for all 4 directions from 8 input rows x 8 cols = 24 immediate-offset
// loads off ONE base address, 16 nontemporal float4 stores. Zero padding
// via wave-coherent predicated loads. Summation order matches the
// previously-passing kernel exactly (d ascending; hor = left-assoc
// 5-chain) -> absmax must stay 0.

typedef float f32x4 __attribute__((ext_vector_type(4)));

constexpr int N = 128, C = 16, H = 128, W = 128;
constexpr int TH = 32;               // output rows per block
constexpr int VB = 4;                // output rows per thread

__global__ __launch_bounds__(256, 4)
void Point2DirSum_kernel(const float* __restrict__ in, float* __restrict__ out) {
    const int tid = threadIdx.x;
    constexpr int TILES_PER_IMG = H / TH;            // 4
    const int img = blockIdx.x / TILES_PER_IMG;      // n*C + c
    const int t   = blockIdx.x % TILES_PER_IMG;
    const int h0  = t * TH;

    // Thread -> output patch: rows hb..hb+3, cols w4..w4+3.
    // Lanes 0-31 of a wave share hb (coalesced 512B store segments).
    const int w4 = (tid & 31) * 4;
    const int hb = h0 + (tid >> 5) * VB;

    // e[k] (per input row) = input col (w4-2+k), k=0..7.
    // base points at (row hb-2, col w4-2); every load is base + imm offset:
    //   row r (r=0..7): +r*W floats; e[0:2] at +0 (8B-aligned float2),
    //   e[2:6] at +2 (16B-aligned float4), e[6:8] at +6 (8B-aligned float2).
    const float* __restrict__ base =
        in + (size_t)img * H * W + (size_t)(hb - 2) * W + (w4 - 2);

    const bool c_lo = (w4 != 0);         // cols w4-2,w4-1 valid?
    const bool c_hi = (w4 != W - 4);     // cols w4+4,w4+5 valid?

    float ve[VB][4], di[VB][4], ad[VB][4], ho[VB][4];
    #pragma unroll
    for (int i = 0; i < VB; ++i)
        #pragma unroll
        for (int j = 0; j < 4; ++j) { ve[i][j] = 0.f; di[i][j] = 0.f; ad[i][j] = 0.f; }

    #pragma unroll
    for (int r = 0; r < VB + 4; ++r) {           // input row = hb-2+r
        const int gr = hb - 2 + r;
        const bool rok = (unsigned)gr < (unsigned)H;  // zero-pad rows
        float e[8];
        #pragma unroll
        for (int k = 0; k < 8; ++k) e[k] = 0.f;
        if (rok) {
            const float* rp = base + r * W;
            const float4 m = *(const float4*)(rp + 2);   // cols w4..w4+3
            e[2] = m.x; e[3] = m.y; e[4] = m.z; e[5] = m.w;
            if (c_lo) { const float2 lo = *(const float2*)(rp);     e[0] = lo.x; e[1] = lo.y; }
            if (c_hi) { const float2 hi = *(const float2*)(rp + 6); e[6] = hi.x; e[7] = hi.y; }
        }
        // Output row i consumes input row r as window index d = r - i.
        //   ver  += e[j+2]; diag += e[j+d]; adiag += e[j+4-d];
        //   hor (d==2) = e[j]+e[j+1]+e[j+2]+e[j+3]+e[j+4]  (left-assoc)
        // d runs ascending per output -> identical FP order to R1 kernel.
        #pragma unroll
        for (int i = 0; i < VB; ++i) {
            const int d = r - i;
            if (d >= 0 && d < 5) {
                #pragma unroll
                for (int j = 0; j < 4; ++j) {
                    ve[i][j] += e[j + 2];
                    di[i][j] += e[j + d];
                    ad[i][j] += e[j + 4 - d];
                }
                if (d == 2) {
                    #pragma unroll
                    for (int j = 0; j < 4; ++j)
                        ho[i][j] = e[j] + e[j + 1] + e[j + 2] + e[j + 3] + e[j + 4];
                }
            }
        }
    }

    const int n = img / C;
    const int c = img - n * C;
    float* __restrict__ outp = out + (((size_t)n * 4 * C + c) * (size_t)H) * W;
    const size_t plane = (size_t)C * H * W;          // stride between dir blocks

    #pragma unroll
    for (int i = 0; i < VB; ++i) {
        const size_t o = (size_t)(hb + i) * W + w4;
        f32x4 vho = { ho[i][0], ho[i][1], ho[i][2], ho[i][3] };
        f32x4 vve = { ve[i][0], ve[i][1], ve[i][2], ve[i][3] };
        f32x4 vdi = { di[i][0], di[i][1], di[i][2], di[i][3] };
        f32x4 vad = { ad[i][0], ad[i][1], ad[i][2], ad[i][3] };
        __builtin_nontemporal_store(vho, (f32x4*)&outp[o]);
        __builtin_nontemporal_store(vve, (f32x4*)&outp[o + plane]);
        __builtin_nontemporal_store(vdi, (f32x4*)&outp[o + 2 * plane]);
        __builtin_nontemporal_store(vad, (f32x4*)&outp[o + 3 * plane]);
    }
}

extern "C" void kernel_launch(void* const* d_in, const int* in_sizes, int n_in,
                              void* d_out, int out_size, void* d_ws, size_t ws_size,
                              hipStream_t stream) {
    const float* in = (const float*)d_in[0];
    float* out = (float*)d_out;
    const int grid = N * C * (H / TH);               // 8192 blocks
    Point2DirSum_kernel<<<grid, 256, 0, stream>>>(in, out);
}